// Round 1
// baseline (1309.093 us; speedup 1.0000x reference)
//
#include <hip/hip_runtime.h>
#include <hip/hip_bf16.h>
#include <math.h>

#define D 64
#define RELS 8

__device__ __forceinline__ unsigned fenc(float f){
  unsigned u = __float_as_uint(f);
  return (u & 0x80000000u) ? ~u : (u | 0x80000000u);
}
__device__ __forceinline__ float fdec(unsigned u){
  return (u & 0x80000000u) ? __uint_as_float(u & 0x7fffffffu) : __uint_as_float(~u);
}
__device__ __forceinline__ float lrelu(float e){ return e > 0.f ? e : 0.2f*e; }

// ---- K_pre: v_src[r]=W[r]@att_src[r], v_dst likewise; bias_sum = b_self + sum_r bias[r]
__global__ void kprep(const float* __restrict__ W, const float* __restrict__ a_src,
                      const float* __restrict__ a_dst, const float* __restrict__ b_self,
                      const float* __restrict__ bias, float* __restrict__ v,
                      float* __restrict__ bsum){
  int r = blockIdx.x, t = threadIdx.x;
  if (r < RELS) {
    const float* Wr = W + (size_t)r*D*D + (size_t)t*D;
    float as = 0.f, ad = 0.f;
    for (int f = 0; f < D; ++f){
      float w = Wr[f];
      as += w * a_src[r*D + f];
      ad += w * a_dst[r*D + f];
    }
    v[r*D + t] = as;
    v[RELS*D + r*D + t] = ad;
  } else {
    float b = b_self[t];
    for (int rr = 0; rr < RELS; ++rr) b += bias[rr*D + t];
    bsum[t] = b;
  }
}

// ---- K1: per-node logits s,d for all relations; init m with self-loop value
__global__ void knode(const float* __restrict__ x, const float* __restrict__ v,
                      float* __restrict__ s_all, float* __restrict__ d_all,
                      unsigned* __restrict__ m_enc, int N){
  __shared__ float vs[2*RELS*D];
  for (int i = threadIdx.x; i < 2*RELS*D; i += blockDim.x) vs[i] = v[i];
  __syncthreads();
  int stride = gridDim.x * blockDim.x;
  for (int n = blockIdx.x*blockDim.x + threadIdx.x; n < N; n += stride){
    float s[RELS], dd[RELS];
    #pragma unroll
    for (int r = 0; r < RELS; ++r){ s[r] = 0.f; dd[r] = 0.f; }
    const float* xr = x + (size_t)n*D;
    for (int k = 0; k < D; k += 4){
      float4 xv = *(const float4*)(xr + k);
      #pragma unroll
      for (int r = 0; r < RELS; ++r){
        s[r]  += xv.x*vs[r*D+k]   + xv.y*vs[r*D+k+1]   + xv.z*vs[r*D+k+2]   + xv.w*vs[r*D+k+3];
        dd[r] += xv.x*vs[RELS*D+r*D+k] + xv.y*vs[RELS*D+r*D+k+1]
               + xv.z*vs[RELS*D+r*D+k+2] + xv.w*vs[RELS*D+r*D+k+3];
      }
    }
    #pragma unroll
    for (int r = 0; r < RELS; ++r){
      s_all[(size_t)r*N + n] = s[r];
      d_all[(size_t)r*N + n] = dd[r];
      m_enc[(size_t)r*N + n] = fenc(lrelu(s[r] + dd[r]));
    }
  }
}

// ---- K2: edge logits e = leaky(s[src]+d[dst]); atomicMax m[dst]; store e
__global__ void kedge_logit(const int* __restrict__ src, const int* __restrict__ dst,
                            const int* __restrict__ et, const float* __restrict__ s_all,
                            const float* __restrict__ d_all, unsigned* __restrict__ m_enc,
                            float* __restrict__ ew, int E, int N){
  int stride = gridDim.x * blockDim.x;
  for (int i = blockIdx.x*blockDim.x + threadIdx.x; i < E; i += stride){
    int r = et[i];
    float e = lrelu(s_all[(size_t)r*N + src[i]] + d_all[(size_t)r*N + dst[i]]);
    ew[i] = e;
    atomicMax(&m_enc[(size_t)r*N + dst[i]], fenc(e));
  }
}

// ---- K3: denom = exp(self_e - m)   (flat over RELS*N)
__global__ void kdenom_init(const float* __restrict__ s_all, const float* __restrict__ d_all,
                            const unsigned* __restrict__ m_enc, float* __restrict__ denom,
                            int NR){
  int stride = gridDim.x * blockDim.x;
  for (int i = blockIdx.x*blockDim.x + threadIdx.x; i < NR; i += stride){
    float e = lrelu(s_all[i] + d_all[i]);
    denom[i] = expf(e - fdec(m_enc[i]));
  }
}

// ---- K4: w = exp(e - m[dst]); store w; atomicAdd denom
__global__ void kedge_w(const int* __restrict__ dst, const int* __restrict__ et,
                        const unsigned* __restrict__ m_enc, float* __restrict__ ew,
                        float* __restrict__ denom, int E, int N){
  int stride = gridDim.x * blockDim.x;
  for (int i = blockIdx.x*blockDim.x + threadIdx.x; i < E; i += stride){
    int r = et[i]; int dn = dst[i];
    float w = expf(ew[i] - fdec(m_enc[(size_t)r*N + dn]));
    ew[i] = w;
    atomicAdd(&denom[(size_t)r*N + dn], w);
  }
}

// ---- K_agg_init: agg[n][:] = alpha_self * x[n][:]   (one 64-lane group per node)
__global__ void kagg_init(const float* __restrict__ x, const float* __restrict__ s_r,
                          const float* __restrict__ d_r, const unsigned* __restrict__ m_r,
                          const float* __restrict__ den_r, float* __restrict__ agg, int N){
  int lane = threadIdx.x & 63;
  int gw = (blockIdx.x*blockDim.x + threadIdx.x) >> 6;
  int nw = (gridDim.x*blockDim.x) >> 6;
  for (int n = gw; n < N; n += nw){
    float e = lrelu(s_r[n] + d_r[n]);
    float a = expf(e - fdec(m_r[n])) / den_r[n];
    agg[(size_t)n*D + lane] = a * x[(size_t)n*D + lane];
  }
}

// ---- K_agg_edge: agg[dst][:] += (w/denom[dst]) * x[src][:]  for edges of relation r
__global__ void kagg_edge(const int* __restrict__ src, const int* __restrict__ dst,
                          const int* __restrict__ et, const float* __restrict__ ew,
                          const float* __restrict__ den_r, const float* __restrict__ x,
                          float* __restrict__ agg, int E, int r){
  int lane = threadIdx.x & 63;
  int gw = (blockIdx.x*blockDim.x + threadIdx.x) >> 6;
  int nw = (gridDim.x*blockDim.x) >> 6;
  for (int i = gw; i < E; i += nw){
    if (et[i] != r) continue;
    int sn = src[i], dn = dst[i];
    float a = ew[i] / den_r[dn];
    atomicAdd(&agg[(size_t)dn*D + lane], a * x[(size_t)sn*D + lane]);
  }
}

// ---- GEMM: 64-col x 64-row tiles, K=64.  MODE 0: out = A@W + bsum.  MODE 1: out += A@W.
template<int MODE>
__global__ void kgemm(const float* __restrict__ A, const float* __restrict__ Wm,
                      const float* __restrict__ bsum, float* __restrict__ out, int N){
  __shared__ float xs[64*68];
  __shared__ float wsh[64*64];
  int t = threadIdx.x;
  int row0 = blockIdx.x * 64;
  #pragma unroll
  for (int i = 0; i < 4; ++i){
    int idx4 = t + i*256;
    int off = idx4*4;
    int row = off >> 6, col = off & 63;
    float4 val = make_float4(0.f,0.f,0.f,0.f);
    if (row0 + row < N) val = *(const float4*)(A + (size_t)(row0+row)*64 + col);
    *(float4*)(&xs[row*68 + col]) = val;
  }
  #pragma unroll
  for (int i = 0; i < 4; ++i){
    int off = (t + i*256)*4;
    *(float4*)(&wsh[off]) = *(const float4*)(Wm + off);
  }
  __syncthreads();
  int tcol = (t & 15)*4;
  int trow = (t >> 4)*4;
  float acc[4][4];
  #pragma unroll
  for (int j = 0; j < 4; ++j)
    #pragma unroll
    for (int c = 0; c < 4; ++c) acc[j][c] = 0.f;
  #pragma unroll 8
  for (int k = 0; k < 64; ++k){
    float4 b = *(const float4*)(&wsh[k*64 + tcol]);
    float a0 = xs[(trow+0)*68 + k];
    float a1 = xs[(trow+1)*68 + k];
    float a2 = xs[(trow+2)*68 + k];
    float a3 = xs[(trow+3)*68 + k];
    acc[0][0] += a0*b.x; acc[0][1] += a0*b.y; acc[0][2] += a0*b.z; acc[0][3] += a0*b.w;
    acc[1][0] += a1*b.x; acc[1][1] += a1*b.y; acc[1][2] += a1*b.z; acc[1][3] += a1*b.w;
    acc[2][0] += a2*b.x; acc[2][1] += a2*b.y; acc[2][2] += a2*b.z; acc[2][3] += a2*b.w;
    acc[3][0] += a3*b.x; acc[3][1] += a3*b.y; acc[3][2] += a3*b.z; acc[3][3] += a3*b.w;
  }
  #pragma unroll
  for (int j = 0; j < 4; ++j){
    int n = row0 + trow + j;
    if (n >= N) break;
    float* op = out + (size_t)n*64 + tcol;
    float4 o;
    if (MODE == 0){
      float4 bb = *(const float4*)(bsum + tcol);
      o = make_float4(acc[j][0]+bb.x, acc[j][1]+bb.y, acc[j][2]+bb.z, acc[j][3]+bb.w);
    } else {
      float4 p = *(const float4*)op;
      o = make_float4(p.x+acc[j][0], p.y+acc[j][1], p.z+acc[j][2], p.w+acc[j][3]);
    }
    *(float4*)op = o;
  }
}

extern "C" void kernel_launch(void* const* d_in, const int* in_sizes, int n_in,
                              void* d_out, int out_size, void* d_ws, size_t ws_size,
                              hipStream_t stream) {
  const float* x      = (const float*)d_in[0];
  const int*   ei     = (const int*)d_in[1];
  const int*   et     = (const int*)d_in[2];
  const float* W_self = (const float*)d_in[3];
  const float* b_self = (const float*)d_in[4];
  const float* W      = (const float*)d_in[5];
  const float* a_src  = (const float*)d_in[6];
  const float* a_dst  = (const float*)d_in[7];
  const float* bias   = (const float*)d_in[8];

  int N = in_sizes[0] / D;
  int E = in_sizes[2];
  float* out = (float*)d_out;

  float* ws     = (float*)d_ws;
  float* v      = ws;                       // 2*RELS*D = 1024
  float* bsum   = ws + 2*RELS*D;            // 64
  float* s_all  = bsum + D;                 // RELS*N
  float* d_all  = s_all + (size_t)RELS*N;   // RELS*N
  unsigned* m_enc = (unsigned*)(d_all + (size_t)RELS*N); // RELS*N
  float* denom  = (float*)m_enc + (size_t)RELS*N;        // RELS*N
  float* ew     = denom + (size_t)RELS*N;   // E
  float* agg    = ew + E;                   // N*D

  const int* srcp = ei;
  const int* dstp = ei + E;

  kprep<<<RELS+1, D, 0, stream>>>(W, a_src, a_dst, b_self, bias, v, bsum);
  knode<<<1024, 256, 0, stream>>>(x, v, s_all, d_all, m_enc, N);
  kedge_logit<<<2048, 256, 0, stream>>>(srcp, dstp, et, s_all, d_all, m_enc, ew, E, N);
  kdenom_init<<<1024, 256, 0, stream>>>(s_all, d_all, m_enc, denom, RELS*N);
  kedge_w<<<2048, 256, 0, stream>>>(dstp, et, m_enc, ew, denom, E, N);

  int gblk = (N + 63) / 64;
  kgemm<0><<<gblk, 256, 0, stream>>>(x, W_self, bsum, out, N);
  for (int r = 0; r < RELS; ++r){
    kagg_init<<<1024, 256, 0, stream>>>(x, s_all + (size_t)r*N, d_all + (size_t)r*N,
                                        m_enc + (size_t)r*N, denom + (size_t)r*N, agg, N);
    kagg_edge<<<2048, 256, 0, stream>>>(srcp, dstp, et, ew, denom + (size_t)r*N, x, agg, E, r);
    kgemm<1><<<gblk, 256, 0, stream>>>(agg, W + (size_t)r*D*D, bsum, out, N);
  }
}

// Round 2
// 954.726 us; speedup vs baseline: 1.3712x; 1.3712x over previous
//
#include <hip/hip_runtime.h>
#include <math.h>

#define D 64
#define RELS 8

__device__ __forceinline__ float lrelu(float e){ return e > 0.f ? e : 0.2f*e; }

// ---- kprep: v_src[r]=W[r]@att_src[r], v_dst likewise; bsum = b_self + sum_r bias[r]
__global__ void kprep(const float* __restrict__ W, const float* __restrict__ a_src,
                      const float* __restrict__ a_dst, const float* __restrict__ b_self,
                      const float* __restrict__ bias, float* __restrict__ v,
                      float* __restrict__ bsum){
  int r = blockIdx.x, t = threadIdx.x;
  if (r < RELS) {
    const float* Wr = W + (size_t)r*D*D + (size_t)t*D;
    float as = 0.f, ad = 0.f;
    for (int f = 0; f < D; ++f){
      float w = Wr[f];
      as += w * a_src[r*D + f];
      ad += w * a_dst[r*D + f];
    }
    v[r*D + t] = as;
    v[RELS*D + r*D + t] = ad;
  } else {
    float b = b_self[t];
    for (int rr = 0; rr < RELS; ++rr) b += bias[rr*D + t];
    bsum[t] = b;
  }
}

// ---- knode: per-node logits s,d for all relations
__global__ void knode(const float* __restrict__ x, const float* __restrict__ v,
                      float* __restrict__ s_all, float* __restrict__ d_all, int N){
  __shared__ float vs[2*RELS*D];
  for (int i = threadIdx.x; i < 2*RELS*D; i += blockDim.x) vs[i] = v[i];
  __syncthreads();
  int stride = gridDim.x * blockDim.x;
  for (int n = blockIdx.x*blockDim.x + threadIdx.x; n < N; n += stride){
    float s[RELS], dd[RELS];
    #pragma unroll
    for (int r = 0; r < RELS; ++r){ s[r] = 0.f; dd[r] = 0.f; }
    const float* xr = x + (size_t)n*D;
    for (int k = 0; k < D; k += 4){
      float4 xv = *(const float4*)(xr + k);
      #pragma unroll
      for (int r = 0; r < RELS; ++r){
        s[r]  += xv.x*vs[r*D+k]   + xv.y*vs[r*D+k+1]   + xv.z*vs[r*D+k+2]   + xv.w*vs[r*D+k+3];
        dd[r] += xv.x*vs[RELS*D+r*D+k] + xv.y*vs[RELS*D+r*D+k+1]
               + xv.z*vs[RELS*D+r*D+k+2] + xv.w*vs[RELS*D+r*D+k+3];
      }
    }
    #pragma unroll
    for (int r = 0; r < RELS; ++r){
      s_all[(size_t)r*N + n] = s[r];
      d_all[(size_t)r*N + n] = dd[r];
    }
  }
}

// ---- khist: count edges per key = dst*RELS + rel
__global__ void khist(const int* __restrict__ dst, const int* __restrict__ et,
                      int* __restrict__ hist, int E){
  int stride = gridDim.x*blockDim.x;
  for (int i = blockIdx.x*blockDim.x+threadIdx.x; i < E; i += stride)
    atomicAdd(&hist[(size_t)dst[i]*RELS + et[i]], 1);
}

// ---- 3-kernel exclusive scan of hist[0..NK) into off[0..NK], off[0]=0
__global__ void kscan1(const int* __restrict__ hist, int* __restrict__ off,
                       int* __restrict__ bsums, int NK){
  __shared__ int tot[256];
  int b = blockIdx.x, t = threadIdx.x;
  int base = b*2048 + t*8;
  int v[8]; int c = 0;
  #pragma unroll
  for (int j = 0; j < 8; ++j){ int idx = base+j; int h = (idx<NK)? hist[idx]:0; c += h; v[j] = c; }
  tot[t] = c; __syncthreads();
  for (int o = 1; o < 256; o <<= 1){
    int add = (t >= o) ? tot[t-o] : 0;
    __syncthreads();
    tot[t] += add;
    __syncthreads();
  }
  int excl = (t == 0) ? 0 : tot[t-1];
  if (t == 255) bsums[b] = tot[255];
  #pragma unroll
  for (int j = 0; j < 8; ++j){ int idx = base+j; if (idx < NK) off[idx+1] = v[j] + excl; }
}

__global__ void kscan2(int* __restrict__ bsums, int NB){
  __shared__ int s[512];
  int t = threadIdx.x;
  s[t] = (t < NB) ? bsums[t] : 0;
  __syncthreads();
  for (int o = 1; o < 512; o <<= 1){
    int add = (t >= o) ? s[t-o] : 0;
    __syncthreads();
    s[t] += add;
    __syncthreads();
  }
  if (t < NB) bsums[t] = (t == 0) ? 0 : s[t-1];
}

__global__ void kscan3(int* __restrict__ off, const int* __restrict__ bsums, int NK){
  int b = blockIdx.x, t = threadIdx.x;
  int add = bsums[b];
  int base = b*2048 + t*8;
  #pragma unroll
  for (int j = 0; j < 8; ++j){ int idx = base+j; if (idx < NK) off[idx+1] += add; }
  if (b == 0 && t == 0) off[0] = 0;
}

// ---- kscatter: place (src, e) records at sorted positions (counting sort)
__global__ void kscatter(const int* __restrict__ src, const int* __restrict__ dst,
                         const int* __restrict__ et, const float* __restrict__ s_all,
                         const float* __restrict__ d_all, int* __restrict__ cur,
                         int* __restrict__ ssrc, float* __restrict__ se, int E, int N){
  int stride = gridDim.x*blockDim.x;
  for (int i = blockIdx.x*blockDim.x+threadIdx.x; i < E; i += stride){
    int r = et[i], dn = dst[i], sn = src[i];
    int pos = atomicAdd(&cur[(size_t)dn*RELS + r], 1);
    ssrc[pos] = sn;
    se[pos] = lrelu(s_all[(size_t)r*N + sn] + d_all[(size_t)r*N + dn]);
  }
}

// ---- kmega: per 64-row tile: for each relation, build softmax-aggregated x-space
// tile in LDS (CSR segments, no atomics), GEMM-accumulate against W_r; self term
// is relation 8 with agg = x. Single out write.
__global__ __launch_bounds__(256, 4) void kmega(const float* __restrict__ x,
    const float* __restrict__ W, const float* __restrict__ W_self,
    const float* __restrict__ s_all, const float* __restrict__ d_all,
    const int* __restrict__ off, const int* __restrict__ ssrc,
    const float* __restrict__ se, const float* __restrict__ bsum,
    float* __restrict__ out, int N){
  __shared__ float ag[64*68];
  __shared__ float wsh[64*64];
  int t = threadIdx.x;
  int row0 = blockIdx.x * 64;
  int wid = t >> 6, lane = t & 63;
  int tcol = (t & 15)*4, trow = (t >> 4)*4;
  float acc[4][4] = {};

  for (int rel = 0; rel < RELS+1; ++rel){
    __syncthreads();   // previous GEMM done with wsh/ag
    const float* Wm = (rel == RELS) ? W_self : (W + (size_t)rel*D*D);
    #pragma unroll
    for (int i = 0; i < 4; ++i){
      int o = (t + i*256)*4;
      *(float4*)(&wsh[o]) = *(const float4*)(Wm + o);
    }
    for (int rl = wid; rl < 64; rl += 4){
      int dn = row0 + rl;
      float val = 0.f;
      if (dn < N){
        if (rel == RELS){
          val = x[(size_t)dn*D + lane];
        } else {
          int key = dn*RELS + rel;
          int s0 = off[key], s1 = off[key+1];
          float eself = lrelu(s_all[(size_t)rel*N + dn] + d_all[(size_t)rel*N + dn]);
          float m = eself;
          for (int i = s0; i < s1; ++i) m = fmaxf(m, se[i]);
          float den = __expf(eself - m);
          float a = den * x[(size_t)dn*D + lane];
          for (int i = s0; i < s1; ++i){
            float w = __expf(se[i] - m);
            a += w * x[(size_t)ssrc[i]*D + lane];
            den += w;
          }
          val = a / den;
        }
      }
      ag[rl*68 + lane] = val;
    }
    __syncthreads();
    #pragma unroll 8
    for (int k = 0; k < 64; ++k){
      float4 b = *(const float4*)(&wsh[k*64 + tcol]);
      float a0 = ag[(trow+0)*68 + k];
      float a1 = ag[(trow+1)*68 + k];
      float a2 = ag[(trow+2)*68 + k];
      float a3 = ag[(trow+3)*68 + k];
      acc[0][0] += a0*b.x; acc[0][1] += a0*b.y; acc[0][2] += a0*b.z; acc[0][3] += a0*b.w;
      acc[1][0] += a1*b.x; acc[1][1] += a1*b.y; acc[1][2] += a1*b.z; acc[1][3] += a1*b.w;
      acc[2][0] += a2*b.x; acc[2][1] += a2*b.y; acc[2][2] += a2*b.z; acc[2][3] += a2*b.w;
      acc[3][0] += a3*b.x; acc[3][1] += a3*b.y; acc[3][2] += a3*b.z; acc[3][3] += a3*b.w;
    }
  }

  float4 bb = *(const float4*)(bsum + tcol);
  #pragma unroll
  for (int j = 0; j < 4; ++j){
    int n = row0 + trow + j;
    if (n < N){
      float4 o = make_float4(acc[j][0]+bb.x, acc[j][1]+bb.y, acc[j][2]+bb.z, acc[j][3]+bb.w);
      *(float4*)(out + (size_t)n*D + tcol) = o;
    }
  }
}

extern "C" void kernel_launch(void* const* d_in, const int* in_sizes, int n_in,
                              void* d_out, int out_size, void* d_ws, size_t ws_size,
                              hipStream_t stream) {
  const float* x      = (const float*)d_in[0];
  const int*   ei     = (const int*)d_in[1];
  const int*   et     = (const int*)d_in[2];
  const float* W_self = (const float*)d_in[3];
  const float* b_self = (const float*)d_in[4];
  const float* W      = (const float*)d_in[5];
  const float* a_src  = (const float*)d_in[6];
  const float* a_dst  = (const float*)d_in[7];
  const float* bias   = (const float*)d_in[8];

  int N = in_sizes[0] / D;
  int E = in_sizes[2];
  int NK = N * RELS;
  float* out = (float*)d_out;

  // workspace layout (all 16B-aligned)
  float* ws    = (float*)d_ws;
  float* v     = ws;                 // 2*RELS*D = 1024
  float* bsum  = v + 2*RELS*D;       // 64
  float* s_all = bsum + D;           // NK
  float* d_all = s_all + (size_t)NK; // NK
  int* hist    = (int*)(d_all + (size_t)NK); // NK
  int* off     = hist + (size_t)NK;          // NK+16 (pad)
  int* cur     = off + (size_t)NK + 16;      // NK
  int* bsums   = cur + (size_t)NK;           // 512
  int* ssrc    = bsums + 512;                // E
  float* se    = (float*)(ssrc + (size_t)E); // E

  const int* srcp = ei;
  const int* dstp = ei + E;

  kprep<<<RELS+1, D, 0, stream>>>(W, a_src, a_dst, b_self, bias, v, bsum);
  knode<<<1024, 256, 0, stream>>>(x, v, s_all, d_all, N);

  hipMemsetAsync(hist, 0, (size_t)NK*sizeof(int), stream);
  khist<<<2048, 256, 0, stream>>>(dstp, et, hist, E);

  int NB = (NK + 2047) / 2048;
  kscan1<<<NB, 256, 0, stream>>>(hist, off, bsums, NK);
  kscan2<<<1, 512, 0, stream>>>(bsums, NB);
  kscan3<<<NB, 256, 0, stream>>>(off, bsums, NK);

  hipMemcpyAsync(cur, off, (size_t)NK*sizeof(int), hipMemcpyDeviceToDevice, stream);
  kscatter<<<2048, 256, 0, stream>>>(srcp, dstp, et, s_all, d_all, cur, ssrc, se, E, N);

  kmega<<<(N + 63)/64, 256, 0, stream>>>(x, W, W_self, s_all, d_all,
                                         off, ssrc, se, bsum, out, N);
}